// Round 6
// baseline (566.516 us; speedup 1.0000x reference)
//
#include <hip/hip_runtime.h>

#define FEAT 64
#define HDIM 128
#define BN_EPS 1e-5f

typedef __attribute__((ext_vector_type(8))) short bf16x8;
typedef __attribute__((ext_vector_type(4))) float f32x4;

__device__ inline unsigned short f2bf(float f) {
    union { float f; unsigned int u; } v;
    v.f = f;
    unsigned int r = (v.u + 0x7FFFu + ((v.u >> 16) & 1u)) >> 16;  // RNE
    return (unsigned short)r;
}
__device__ inline float bf2f(unsigned short b) {
    union { unsigned int u; float f; } v;
    v.u = ((unsigned int)b) << 16;
    return v.f;
}

// ws layout (float/int units):
//   [0:256)   bn stats: colsum, colsumsq, scale, shift
//   countOff = 256          : count (N ints)
//   rowStartOff = +N        : rowStart (N+1 ints, node-order exclusive scan)
//   cursorOff = +N+1        : fineCursor (N ints)
//   bsumOff = +N            : block sums for scan (512 ints)
//   pcOff = +512            : pairCursor (2048 ints)
//   wcOff (align4)          : Wc bf16 frag-order (8192 floats)
//   xnOff                   : xn bf16 [N][64] (N*32 floats)
//   aggOff                  : agg bf16 [N][64] (N*32 floats); pairs (E ints) ALIASES this
//   srcOff                  : sortedSrc (E ints)

// ---------------- K0: zero stats + count ----------------
__global__ void k0_zero(float* __restrict__ ws, int N) {
    int stride = gridDim.x * blockDim.x;
    int gid = blockIdx.x * blockDim.x + threadIdx.x;
    for (int i = gid; i < 256 + N; i += stride) ws[i] = 0.0f;
}

// ---------------- K1: column sums / sumsq ----------------
__global__ __launch_bounds__(256) void k1_stats(const float* __restrict__ x,
                                                float* __restrict__ ws, int N) {
    int col = threadIdx.x & 63;
    int rowInBlk = threadIdx.x >> 6;
    float s = 0.f, sq = 0.f;
    for (int r = blockIdx.x * 4 + rowInBlk; r < N; r += gridDim.x * 4) {
        float v = x[(size_t)r * FEAT + col];
        s += v;
        sq += v * v;
    }
    __shared__ float sd[256];
    __shared__ float sd2[256];
    sd[threadIdx.x] = s;
    sd2[threadIdx.x] = sq;
    __syncthreads();
    if (threadIdx.x < 64) {
        s = sd[col] + sd[col + 64] + sd[col + 128] + sd[col + 192];
        sq = sd2[col] + sd2[col + 64] + sd2[col + 128] + sd2[col + 192];
        atomicAdd(&ws[col], s);
        atomicAdd(&ws[64 + col], sq);
    }
}

// ---------------- K2: finalize scale/shift ----------------
__global__ void k2_finalize(float* __restrict__ ws, const float* __restrict__ gamma,
                            const float* __restrict__ beta, int N) {
    int c = threadIdx.x;  // 64 threads
    float invN = 1.0f / (float)N;
    float mean = ws[c] * invN;
    float var = ws[64 + c] * invN - mean * mean;
    float sc = rsqrtf(var + BN_EPS) * gamma[c];
    ws[128 + c] = sc;
    ws[192 + c] = beta[c] - mean * sc;
}

// ---------------- K3: xn = bf16(x*scale + shift) ----------------
__global__ __launch_bounds__(256) void k3_norm(const float* __restrict__ x,
                                               const float* __restrict__ ws,
                                               unsigned short* __restrict__ xn, int N) {
    const float4* x4 = (const float4*)x;
    ushort4* o4 = (ushort4*)xn;
    int n4 = N * (FEAT / 4);
    int stride = gridDim.x * blockDim.x;
    for (int i = blockIdx.x * blockDim.x + threadIdx.x; i < n4; i += stride) {
        int cg = (i & 15) << 2;
        float4 v = x4[i];
        float4 sc = *(const float4*)(ws + 128 + cg);
        float4 sh = *(const float4*)(ws + 192 + cg);
        ushort4 o;
        o.x = f2bf(v.x * sc.x + sh.x);
        o.y = f2bf(v.y * sc.y + sh.y);
        o.z = f2bf(v.z * sc.z + sh.z);
        o.w = f2bf(v.w * sc.w + sh.w);
        o4[i] = o;
    }
}

// ---------------- KW: pack weights, MFMA-fragment order ----------------
__global__ __launch_bounds__(256) void kw_conv(const float* __restrict__ Wl,
                                               const float* __restrict__ Wr,
                                               unsigned short* __restrict__ Wc) {
    int id = blockIdx.x * 256 + threadIdx.x;  // 16384 total
    int n = id >> 7, k = id & 127;
    float w = (k < 64) ? Wl[k * HDIM + n] : Wr[(k - 64) * HDIM + n];
    Wc[((k >> 5) * 128 + n) * 32 + (k & 31)] = f2bf(w);
}

// ---------------- K4a: fine histogram of dst ----------------
__global__ __launch_bounds__(256) void k4a_hist(const int* __restrict__ ei,
                                                int* __restrict__ count, int E) {
    int e = blockIdx.x * 256 + threadIdx.x;
    if (e < E) atomicAdd(&count[ei[E + e]], 1);
}

// ---------------- S1: per-block sums of count ----------------
__global__ __launch_bounds__(256) void s1_blocksum(const int* __restrict__ count,
                                                   int* __restrict__ bsum, int N) {
    __shared__ int sd[256];
    int i = blockIdx.x * 256 + threadIdx.x;
    sd[threadIdx.x] = (i < N) ? count[i] : 0;
    __syncthreads();
    for (int off = 128; off > 0; off >>= 1) {
        if (threadIdx.x < off) sd[threadIdx.x] += sd[threadIdx.x + off];
        __syncthreads();
    }
    if (threadIdx.x == 0) bsum[blockIdx.x] = sd[0];
}

// ---------------- S2: scan block sums (single block, 512 wide) ----------------
__global__ __launch_bounds__(512) void s2_scan(int* __restrict__ bsum, int nb) {
    __shared__ int sd[512];
    int t = threadIdx.x;
    int c = (t < nb) ? bsum[t] : 0;
    sd[t] = c;
    __syncthreads();
    int v = c;
    for (int off = 1; off < 512; off <<= 1) {
        int add = (t >= off) ? sd[t - off] : 0;
        __syncthreads();
        v += add;
        sd[t] = v;
        __syncthreads();
    }
    if (t < nb) bsum[t] = v - c;  // exclusive
}

// ---------------- S3: rowStart/cursor = node-order exclusive scan ----------------
__global__ __launch_bounds__(256) void s3_scatter(const int* __restrict__ count,
                                                  const int* __restrict__ bsum,
                                                  int* __restrict__ rowStart,
                                                  int* __restrict__ cursor,
                                                  int N, int E) {
    __shared__ int sd[256];
    int i = blockIdx.x * 256 + threadIdx.x;
    int c = (i < N) ? count[i] : 0;
    sd[threadIdx.x] = c;
    __syncthreads();
    int v = c;
    for (int off = 1; off < 256; off <<= 1) {
        int add = (threadIdx.x >= off) ? sd[threadIdx.x - off] : 0;
        __syncthreads();
        v += add;
        sd[threadIdx.x] = v;
        __syncthreads();
    }
    if (i < N) {
        int st = bsum[blockIdx.x] + v - c;
        rowStart[i] = st;
        cursor[i] = st;
    }
    if (i == 0) rowStart[N] = E;
}

// ---------------- KPC: init coarse pair cursors ----------------
__global__ __launch_bounds__(256) void kpc_init(const int* __restrict__ rowStart,
                                                int* __restrict__ pairCursor, int nb) {
    int b = blockIdx.x * 256 + threadIdx.x;
    if (b < nb) pairCursor[b] = rowStart[b * 64];
}

// ---------------- KC: coarse scatter (src<<6 | dst&63) into bucket regions ----
__global__ __launch_bounds__(256) void kc_coarse(const int* __restrict__ ei,
                                                 int* __restrict__ pairCursor,
                                                 int* __restrict__ pairs, int E) {
    int e = blockIdx.x * 256 + threadIdx.x;
    if (e >= E) return;
    int src = ei[e];
    int dst = ei[E + e];
    int pos = atomicAdd(&pairCursor[dst >> 6], 1);
    pairs[pos] = (src << 6) | (dst & 63);
}

// ---------------- KD: fine scatter within bucket (one block per bucket) -------
__global__ __launch_bounds__(256) void kd_fine(const int* __restrict__ pairs,
                                               const int* __restrict__ rowStart,
                                               int* __restrict__ cursor,
                                               int* __restrict__ sortedSrc,
                                               int N, int nb) {
    int b = blockIdx.x;
    int base = b * 64;
    int bs = rowStart[base];
    int be = rowStart[min(base + 64, N)];
    for (int i = bs + threadIdx.x; i < be; i += 256) {
        int p = pairs[i];
        int dst = base + (p & 63);
        int pos = atomicAdd(&cursor[dst], 1);
        sortedSrc[pos] = p & ~63;  // == src * 64 (ushort row offset)
    }
}

// ---------------- K4d: gather + mean, vectorized (bf16x8 loads) ----------------
// one wave per node; lane = (slot = lane>>3 edge-in-chunk, part = lane&7 col slice)
__global__ __launch_bounds__(256) void k4d_gather(const int* __restrict__ sortedSrc,
                                                  const int* __restrict__ rowStart,
                                                  const int* __restrict__ count,
                                                  const unsigned short* __restrict__ xn,
                                                  unsigned short* __restrict__ agg,
                                                  int N) {
    int node = blockIdx.x * 4 + (threadIdx.x >> 6);
    if (node >= N) return;
    int lane = threadIdx.x & 63;
    int part = lane & 7;
    int slot = lane >> 3;
    int start = rowStart[node];
    int deg = count[node];
    float acc[8];
#pragma unroll
    for (int j = 0; j < 8; j++) acc[j] = 0.f;
    for (int e = 0; e < deg; e += 8) {
        if (e + slot < deg) {
            int s = sortedSrc[start + e + slot];  // src*64
            bf16x8 v = *(const bf16x8*)(xn + s + part * 8);
#pragma unroll
            for (int j = 0; j < 8; j++) acc[j] += bf2f((unsigned short)v[j]);
        }
    }
    // reduce across slots (lanes 8 apart share the same part)
#pragma unroll
    for (int m = 8; m <= 32; m <<= 1)
#pragma unroll
        for (int j = 0; j < 8; j++) acc[j] += __shfl_xor(acc[j], m);
    if (slot == 0) {
        float dinv = (deg > 0) ? (1.0f / (float)deg) : 0.0f;
        union { bf16x8 v; unsigned short u[8]; } o;
#pragma unroll
        for (int j = 0; j < 8; j++) o.u[j] = f2bf(acc[j] * dinv);
        *(bf16x8*)(agg + (size_t)node * FEAT + part * 8) = o.v;
    }
}

// ---------------- K5: MFMA GEMM (bf16) + fused head ----------------
#define HS 133  // h_s row stride (floats)

__global__ __launch_bounds__(256, 4) void k5_gemm(
    const unsigned short* __restrict__ agg, const unsigned short* __restrict__ xn,
    const unsigned short* __restrict__ Wc, const float* __restrict__ bl,
    const float* __restrict__ W1, const float* __restrict__ b1,
    const float* __restrict__ W2, const float* __restrict__ b2,
    float* __restrict__ out, int N) {
    __shared__ float h_s[64 * HS];  // ~34 KB
    int t = threadIdx.x;
    int lane = t & 63;
    int wv = t >> 6;
    int rh = wv & 1;
    int ch = wv >> 1;
    int c = lane & 15;
    int q = lane >> 4;
    int row0 = blockIdx.x * 64;

    f32x4 acc[2][4];
    f32x4 z = {0.f, 0.f, 0.f, 0.f};
#pragma unroll
    for (int rt = 0; rt < 2; rt++)
#pragma unroll
        for (int nt = 0; nt < 4; nt++) acc[rt][nt] = z;

#pragma unroll 1
    for (int kt = 0; kt < 4; kt++) {
        bf16x8 bfr[4];
#pragma unroll
        for (int nt = 0; nt < 4; nt++) {
            int col = ch * 64 + nt * 16 + c;
            bfr[nt] = *(const bf16x8*)(Wc + ((size_t)kt * 128 + col) * 32 + q * 8);
        }
        const unsigned short* src = (kt < 2) ? agg : xn;
        int ko = (kt & 1) * 32 + q * 8;
        bf16x8 af[2];
#pragma unroll
        for (int rt = 0; rt < 2; rt++) {
            int row = row0 + rh * 32 + rt * 16 + c;
            row = min(row, N - 1);
            af[rt] = *(const bf16x8*)(src + (size_t)row * FEAT + ko);
        }
#pragma unroll
        for (int rt = 0; rt < 2; rt++)
#pragma unroll
            for (int nt = 0; nt < 4; nt++)
                acc[rt][nt] = __builtin_amdgcn_mfma_f32_16x16x32_bf16(
                    af[rt], bfr[nt], acc[rt][nt], 0, 0, 0);
    }

#pragma unroll
    for (int rt = 0; rt < 2; rt++) {
        int rbase = rh * 32 + rt * 16 + q * 4;
#pragma unroll
        for (int nt = 0; nt < 4; nt++) {
            int col = ch * 64 + nt * 16 + c;
            float bias = bl[col];
#pragma unroll
            for (int r = 0; r < 4; r++)
                h_s[(rbase + r) * HS + col] = fmaxf(acc[rt][nt][r] + bias, 0.f);
        }
    }
    __syncthreads();

    int row = t & 63;
    int jg = t >> 6;
    int j0 = jg * 32;
    float tp[16];
#pragma unroll
    for (int m = 0; m < 16; m++) tp[m] = 0.f;
    for (int jj = 0; jj < 32; jj++) {
        float hv = h_s[row * HS + j0 + jj];
        const float4* w14 = (const float4*)(W1 + (j0 + jj) * 16);
#pragma unroll
        for (int qq = 0; qq < 4; qq++) {
            float4 w1 = w14[qq];
            tp[4 * qq + 0] += hv * w1.x;
            tp[4 * qq + 1] += hv * w1.y;
            tp[4 * qq + 2] += hv * w1.z;
            tp[4 * qq + 3] += hv * w1.w;
        }
    }
    __syncthreads();
#pragma unroll
    for (int m = 0; m < 16; m++) h_s[row * HS + jg * 16 + m] = tp[m];
    __syncthreads();

    if (t < 64) {
        int rowg = row0 + t;
        if (rowg < N) {
            float o0 = b2[0], o1 = b2[1];
#pragma unroll
            for (int m = 0; m < 16; m++) {
                float tm = b1[m] + h_s[t * HS + m] + h_s[t * HS + 16 + m] +
                           h_s[t * HS + 32 + m] + h_s[t * HS + 48 + m];
                tm = fmaxf(tm, 0.f);
                o0 += tm * W2[m * 2 + 0];
                o1 += tm * W2[m * 2 + 1];
            }
            out[(size_t)rowg * 2 + 0] = o0;
            out[(size_t)rowg * 2 + 1] = o1;
        }
    }
}

extern "C" void kernel_launch(void* const* d_in, const int* in_sizes, int n_in,
                              void* d_out, int out_size, void* d_ws, size_t ws_size,
                              hipStream_t stream) {
    const float* x = (const float*)d_in[0];
    const int* ei = (const int*)d_in[1];
    const float* gamma = (const float*)d_in[6];
    const float* beta = (const float*)d_in[7];
    const float* Wl = (const float*)d_in[8];
    const float* bl = (const float*)d_in[9];
    const float* Wr = (const float*)d_in[10];
    const float* W1 = (const float*)d_in[11];
    const float* b1 = (const float*)d_in[12];
    const float* W2 = (const float*)d_in[13];
    const float* b2 = (const float*)d_in[14];

    int N = in_sizes[0] / FEAT;   // 100000
    int E = in_sizes[1] / 2;      // 1200000
    int nb = (N + 63) >> 6;       // coarse buckets (64 nodes each)
    int nsb = (N + 255) >> 8;     // scan blocks

    float* ws = (float*)d_ws;
    int* wsi = (int*)d_ws;
    int countOff = 256;
    int rowStartOff = countOff + N;        // N+1 ints
    int cursorOff = rowStartOff + N + 1;   // N ints
    int bsumOff = cursorOff + N;           // 512 ints
    int pcOff = bsumOff + 512;             // 2048 ints
    int wcOff = (pcOff + 2048 + 3) & ~3;   // 8192 floats (Wc: 16384 ushorts)
    int xnOff = wcOff + 8192;              // N*32 floats
    int aggOff = xnOff + N * 32;           // N*32 floats; pairs aliases here
    int srcOff = aggOff + N * 32;          // E ints

    unsigned short* xnp = (unsigned short*)(ws + xnOff);
    unsigned short* aggp = (unsigned short*)(ws + aggOff);
    unsigned short* wcp = (unsigned short*)(ws + wcOff);
    int* pairs = wsi + aggOff;  // aliases agg (consumed before k4d writes agg)

    float* out = (float*)d_out;

    hipLaunchKernelGGL(k0_zero, dim3(512), dim3(256), 0, stream, ws, N);
    hipLaunchKernelGGL(k1_stats, dim3(1024), dim3(256), 0, stream, x, ws, N);
    hipLaunchKernelGGL(k2_finalize, dim3(1), dim3(64), 0, stream, ws, gamma, beta, N);
    hipLaunchKernelGGL(kw_conv, dim3(64), dim3(256), 0, stream, Wl, Wr, wcp);
    hipLaunchKernelGGL(k3_norm, dim3(2048), dim3(256), 0, stream, x, ws, xnp, N);

    int eb = (E + 255) / 256;
    hipLaunchKernelGGL(k4a_hist, dim3(eb), dim3(256), 0, stream, ei, wsi + countOff, E);
    hipLaunchKernelGGL(s1_blocksum, dim3(nsb), dim3(256), 0, stream,
                       wsi + countOff, wsi + bsumOff, N);
    hipLaunchKernelGGL(s2_scan, dim3(1), dim3(512), 0, stream, wsi + bsumOff, nsb);
    hipLaunchKernelGGL(s3_scatter, dim3(nsb), dim3(256), 0, stream,
                       wsi + countOff, wsi + bsumOff, wsi + rowStartOff,
                       wsi + cursorOff, N, E);
    hipLaunchKernelGGL(kpc_init, dim3((nb + 255) / 256), dim3(256), 0, stream,
                       wsi + rowStartOff, wsi + pcOff, nb);
    hipLaunchKernelGGL(kc_coarse, dim3(eb), dim3(256), 0, stream, ei, wsi + pcOff,
                       pairs, E);
    hipLaunchKernelGGL(kd_fine, dim3(nb), dim3(256), 0, stream, pairs,
                       wsi + rowStartOff, wsi + cursorOff, wsi + srcOff, N, nb);
    hipLaunchKernelGGL(k4d_gather, dim3((N + 3) / 4), dim3(256), 0, stream,
                       wsi + srcOff, wsi + rowStartOff, wsi + countOff,
                       xnp, aggp, N);

    hipLaunchKernelGGL(k5_gemm, dim3((N + 63) / 64), dim3(256), 0, stream,
                       aggp, xnp, wcp, bl, W1, b1, W2, b2, out, N);
}

// Round 7
// 362.029 us; speedup vs baseline: 1.5648x; 1.5648x over previous
//
#include <hip/hip_runtime.h>

#define FEAT 64
#define HDIM 128
#define BN_EPS 1e-5f

#define BSH 7          // 128 nodes per coarse bucket
#define NB_MAX 1024    // max buckets (N <= 131072)
#define CHUNK 8192     // edges per binning block
#define SEG 4096       // LDS pair capacity in kda

typedef __attribute__((ext_vector_type(8))) short bf16x8;
typedef __attribute__((ext_vector_type(4))) float f32x4;

__device__ inline unsigned short f2bf(float f) {
    union { float f; unsigned int u; } v;
    v.f = f;
    unsigned int r = (v.u + 0x7FFFu + ((v.u >> 16) & 1u)) >> 16;  // RNE
    return (unsigned short)r;
}
__device__ inline float bf2f(unsigned short b) {
    union { unsigned int u; float f; } v;
    v.u = ((unsigned int)b) << 16;
    return v.f;
}

// ws layout (float/int units):
//   [0:256)    bn stats: colsum, colsumsq, scale, shift
//   bcOff=256  : bucketCnt (1024 ints)
//   bsOff=1280 : bucketStart (1025 ints)
//   pcOff=2336 : pairCursor (1024 ints)
//   wcOff=3360 : Wc bf16 frag-order (8192 floats)
//   xnOff      : xn bf16 [N][64]  (N*32 floats)
//   aggOff     : agg bf16 [N][64] (N*32 floats)
//   pairsOff   : pairs (E ints)   -- distinct from agg (lifetimes overlap in kda)

// ---------------- K0: zero stats + bucketCnt ----------------
__global__ void k0_zero(float* __restrict__ ws) {
    int gid = blockIdx.x * blockDim.x + threadIdx.x;
    if (gid < 256 + NB_MAX) ws[gid] = 0.0f;
}

// ---------------- K1: column sums / sumsq ----------------
__global__ __launch_bounds__(256) void k1_stats(const float* __restrict__ x,
                                                float* __restrict__ ws, int N) {
    int col = threadIdx.x & 63;
    int rowInBlk = threadIdx.x >> 6;
    float s = 0.f, sq = 0.f;
    for (int r = blockIdx.x * 4 + rowInBlk; r < N; r += gridDim.x * 4) {
        float v = x[(size_t)r * FEAT + col];
        s += v;
        sq += v * v;
    }
    __shared__ float sd[256];
    __shared__ float sd2[256];
    sd[threadIdx.x] = s;
    sd2[threadIdx.x] = sq;
    __syncthreads();
    if (threadIdx.x < 64) {
        s = sd[col] + sd[col + 64] + sd[col + 128] + sd[col + 192];
        sq = sd2[col] + sd2[col + 64] + sd2[col + 128] + sd2[col + 192];
        atomicAdd(&ws[col], s);
        atomicAdd(&ws[64 + col], sq);
    }
}

// ---------------- K2: finalize scale/shift ----------------
__global__ void k2_finalize(float* __restrict__ ws, const float* __restrict__ gamma,
                            const float* __restrict__ beta, int N) {
    int c = threadIdx.x;  // 64 threads
    float invN = 1.0f / (float)N;
    float mean = ws[c] * invN;
    float var = ws[64 + c] * invN - mean * mean;
    float sc = rsqrtf(var + BN_EPS) * gamma[c];
    ws[128 + c] = sc;
    ws[192 + c] = beta[c] - mean * sc;
}

// ---------------- K3: xn = bf16(x*scale + shift) ----------------
__global__ __launch_bounds__(256) void k3_norm(const float* __restrict__ x,
                                               const float* __restrict__ ws,
                                               unsigned short* __restrict__ xn, int N) {
    const float4* x4 = (const float4*)x;
    ushort4* o4 = (ushort4*)xn;
    int n4 = N * (FEAT / 4);
    int stride = gridDim.x * blockDim.x;
    for (int i = blockIdx.x * blockDim.x + threadIdx.x; i < n4; i += stride) {
        int cg = (i & 15) << 2;
        float4 v = x4[i];
        float4 sc = *(const float4*)(ws + 128 + cg);
        float4 sh = *(const float4*)(ws + 192 + cg);
        ushort4 o;
        o.x = f2bf(v.x * sc.x + sh.x);
        o.y = f2bf(v.y * sc.y + sh.y);
        o.z = f2bf(v.z * sc.z + sh.z);
        o.w = f2bf(v.w * sc.w + sh.w);
        o4[i] = o;
    }
}

// ---------------- KW: pack weights, MFMA-fragment order ----------------
__global__ __launch_bounds__(256) void kw_conv(const float* __restrict__ Wl,
                                               const float* __restrict__ Wr,
                                               unsigned short* __restrict__ Wc) {
    int id = blockIdx.x * 256 + threadIdx.x;  // 16384 total
    int n = id >> 7, k = id & 127;
    float w = (k < 64) ? Wl[k * HDIM + n] : Wr[(k - 64) * HDIM + n];
    Wc[((k >> 5) * 128 + n) * 32 + (k & 31)] = f2bf(w);
}

// ---------------- KBH: bucket histogram, block-aggregated ----------------
__global__ __launch_bounds__(256) void kbh(const int* __restrict__ ei,
                                           int* __restrict__ bktCnt, int E, int nb) {
    __shared__ int hist[NB_MAX];
    int e0 = blockIdx.x * CHUNK;
    int e1 = min(E, e0 + CHUNK);
    for (int b = threadIdx.x; b < nb; b += 256) hist[b] = 0;
    __syncthreads();
    for (int e = e0 + threadIdx.x; e < e1; e += 256)
        atomicAdd(&hist[((unsigned)ei[E + e]) >> BSH], 1);
    __syncthreads();
    for (int b = threadIdx.x; b < nb; b += 256) {
        int c = hist[b];
        if (c) atomicAdd(&bktCnt[b], c);
    }
}

// ---------------- KBSCAN: scan bucket counts, init cursors ----------------
__global__ __launch_bounds__(1024) void kbscan(const int* __restrict__ bktCnt,
                                               int* __restrict__ bktStart,
                                               int* __restrict__ pairCursor, int nb) {
    __shared__ int sd[1024];
    int t = threadIdx.x;
    int c = (t < nb) ? bktCnt[t] : 0;
    sd[t] = c;
    __syncthreads();
    int v = c;
    for (int off = 1; off < 1024; off <<= 1) {
        int add = (t >= off) ? sd[t - off] : 0;
        __syncthreads();
        v += add;
        sd[t] = v;
        __syncthreads();
    }
    if (t <= nb) {
        int st = v - c;  // exclusive prefix (t==nb -> total E)
        bktStart[t] = st;
        if (t < nb) pairCursor[t] = st;
    }
}

// ---------------- KC: coarse scatter, block-aggregated ----------------
// one reservation atomic per (block,bucket); pair runs are block-private.
__global__ __launch_bounds__(256) void kc_bin(const int* __restrict__ ei,
                                              int* __restrict__ pairCursor,
                                              int* __restrict__ pairs, int E, int nb) {
    __shared__ int hist[NB_MAX];
    __shared__ int base[NB_MAX];
    int e0 = blockIdx.x * CHUNK;
    int e1 = min(E, e0 + CHUNK);
    for (int b = threadIdx.x; b < nb; b += 256) hist[b] = 0;
    __syncthreads();
    for (int e = e0 + threadIdx.x; e < e1; e += 256)
        atomicAdd(&hist[((unsigned)ei[E + e]) >> BSH], 1);
    __syncthreads();
    for (int b = threadIdx.x; b < nb; b += 256) {
        int c = hist[b];
        base[b] = c ? atomicAdd(&pairCursor[b], c) : 0;
        hist[b] = 0;  // reuse as local cursor
    }
    __syncthreads();
    for (int e = e0 + threadIdx.x; e < e1; e += 256) {
        int src = ei[e];
        int dst = ei[E + e];
        int b = ((unsigned)dst) >> BSH;
        int off = atomicAdd(&hist[b], 1);
        pairs[base[b] + off] = (src << BSH) | (dst & 127);
    }
}

// ---------------- KDA: fused fine-group (LDS) + gather + mean ----------------
// one block per 128-node bucket; pairs grouped by node in LDS; vectorized gather.
__global__ __launch_bounds__(256) void kda(const int* __restrict__ pairs,
                                           const int* __restrict__ bktStart,
                                           const unsigned short* __restrict__ xn,
                                           unsigned short* __restrict__ agg, int N) {
    __shared__ int sidx[SEG];
    __shared__ int cnt[128], nstart[128], ncur[128], buf[128];
    int b = blockIdx.x;
    int base = b << BSH;
    int bs = bktStart[b], be = bktStart[b + 1];
    int total = be - bs;
    int t = threadIdx.x;
    int lane = t & 63, wv = t >> 6;
    int part = lane & 7, slot = lane >> 3;

    if (total <= SEG) {
        // --- fast path: group pairs by node in LDS ---
        if (t < 128) cnt[t] = 0;
        __syncthreads();
        for (int i = bs + t; i < be; i += 256)
            atomicAdd(&cnt[pairs[i] & 127], 1);
        __syncthreads();
        int v = 0, c = 0;
        if (t < 128) { c = cnt[t]; buf[t] = c; }
        __syncthreads();
        v = c;
        for (int off = 1; off < 128; off <<= 1) {
            int add = (t < 128 && t >= off) ? buf[t - off] : 0;
            __syncthreads();
            if (t < 128) { v += add; buf[t] = v; }
            __syncthreads();
        }
        if (t < 128) {
            nstart[t] = v - c;
            ncur[t] = v - c;
        }
        __syncthreads();
        for (int i = bs + t; i < be; i += 256) {
            int p = pairs[i];
            int nid = p & 127;
            int pos = atomicAdd(&ncur[nid], 1);
            sidx[pos] = (p >> BSH) << 6;  // src row offset in ushorts
        }
        __syncthreads();
        // --- vectorized gather: wave per node, lane = (slot, part) ---
        for (int ni = wv; ni < 128; ni += 4) {
            int node = base + ni;
            if (node >= N) continue;
            int st = nstart[ni];
            int deg = cnt[ni];
            float acc[8];
#pragma unroll
            for (int j = 0; j < 8; j++) acc[j] = 0.f;
            for (int e = 0; e < deg; e += 8) {
                if (e + slot < deg) {
                    int s = sidx[st + e + slot];
                    bf16x8 vx = *(const bf16x8*)(xn + s + part * 8);
#pragma unroll
                    for (int j = 0; j < 8; j++) acc[j] += bf2f((unsigned short)vx[j]);
                }
            }
#pragma unroll
            for (int m = 8; m <= 32; m <<= 1)
#pragma unroll
                for (int j = 0; j < 8; j++) acc[j] += __shfl_xor(acc[j], m);
            if (slot == 0) {
                float dinv = (deg > 0) ? (1.0f / (float)deg) : 0.0f;
                union { bf16x8 v; unsigned short u[8]; } o;
#pragma unroll
                for (int j = 0; j < 8; j++) o.u[j] = f2bf(acc[j] * dinv);
                *(bf16x8*)(agg + (size_t)node * FEAT + part * 8) = o.v;
            }
        }
    } else {
        // --- slow path (bucket > SEG pairs; statistically never hit): scalar scan ---
        for (int ni = wv; ni < 128; ni += 4) {
            int node = base + ni;
            if (node >= N) continue;
            float acc = 0.f;
            int deg = 0;
            for (int i = bs; i < be; i++) {
                int p = pairs[i];
                if ((p & 127) == ni) {
                    acc += bf2f(xn[((p >> BSH) << 6) + lane]);
                    deg++;
                }
            }
            float dinv = (deg > 0) ? (1.0f / (float)deg) : 0.0f;
            agg[(size_t)node * FEAT + lane] = f2bf(acc * dinv);
        }
    }
}

// ---------------- K5: MFMA GEMM (bf16) + fused head ----------------
#define HS 133  // h_s row stride (floats)

__global__ __launch_bounds__(256, 4) void k5_gemm(
    const unsigned short* __restrict__ agg, const unsigned short* __restrict__ xn,
    const unsigned short* __restrict__ Wc, const float* __restrict__ bl,
    const float* __restrict__ W1, const float* __restrict__ b1,
    const float* __restrict__ W2, const float* __restrict__ b2,
    float* __restrict__ out, int N) {
    __shared__ float h_s[64 * HS];  // ~34 KB
    int t = threadIdx.x;
    int lane = t & 63;
    int wv = t >> 6;
    int rh = wv & 1;
    int ch = wv >> 1;
    int c = lane & 15;
    int q = lane >> 4;
    int row0 = blockIdx.x * 64;

    f32x4 acc[2][4];
    f32x4 z = {0.f, 0.f, 0.f, 0.f};
#pragma unroll
    for (int rt = 0; rt < 2; rt++)
#pragma unroll
        for (int nt = 0; nt < 4; nt++) acc[rt][nt] = z;

#pragma unroll 1
    for (int kt = 0; kt < 4; kt++) {
        bf16x8 bfr[4];
#pragma unroll
        for (int nt = 0; nt < 4; nt++) {
            int col = ch * 64 + nt * 16 + c;
            bfr[nt] = *(const bf16x8*)(Wc + ((size_t)kt * 128 + col) * 32 + q * 8);
        }
        const unsigned short* src = (kt < 2) ? agg : xn;
        int ko = (kt & 1) * 32 + q * 8;
        bf16x8 af[2];
#pragma unroll
        for (int rt = 0; rt < 2; rt++) {
            int row = row0 + rh * 32 + rt * 16 + c;
            row = min(row, N - 1);
            af[rt] = *(const bf16x8*)(src + (size_t)row * FEAT + ko);
        }
#pragma unroll
        for (int rt = 0; rt < 2; rt++)
#pragma unroll
            for (int nt = 0; nt < 4; nt++)
                acc[rt][nt] = __builtin_amdgcn_mfma_f32_16x16x32_bf16(
                    af[rt], bfr[nt], acc[rt][nt], 0, 0, 0);
    }

#pragma unroll
    for (int rt = 0; rt < 2; rt++) {
        int rbase = rh * 32 + rt * 16 + q * 4;
#pragma unroll
        for (int nt = 0; nt < 4; nt++) {
            int col = ch * 64 + nt * 16 + c;
            float bias = bl[col];
#pragma unroll
            for (int r = 0; r < 4; r++)
                h_s[(rbase + r) * HS + col] = fmaxf(acc[rt][nt][r] + bias, 0.f);
        }
    }
    __syncthreads();

    int row = t & 63;
    int jg = t >> 6;
    int j0 = jg * 32;
    float tp[16];
#pragma unroll
    for (int m = 0; m < 16; m++) tp[m] = 0.f;
    for (int jj = 0; jj < 32; jj++) {
        float hv = h_s[row * HS + j0 + jj];
        const float4* w14 = (const float4*)(W1 + (j0 + jj) * 16);
#pragma unroll
        for (int qq = 0; qq < 4; qq++) {
            float4 w1 = w14[qq];
            tp[4 * qq + 0] += hv * w1.x;
            tp[4 * qq + 1] += hv * w1.y;
            tp[4 * qq + 2] += hv * w1.z;
            tp[4 * qq + 3] += hv * w1.w;
        }
    }
    __syncthreads();
#pragma unroll
    for (int m = 0; m < 16; m++) h_s[row * HS + jg * 16 + m] = tp[m];
    __syncthreads();

    if (t < 64) {
        int rowg = row0 + t;
        if (rowg < N) {
            float o0 = b2[0], o1 = b2[1];
#pragma unroll
            for (int m = 0; m < 16; m++) {
                float tm = b1[m] + h_s[t * HS + m] + h_s[t * HS + 16 + m] +
                           h_s[t * HS + 32 + m] + h_s[t * HS + 48 + m];
                tm = fmaxf(tm, 0.f);
                o0 += tm * W2[m * 2 + 0];
                o1 += tm * W2[m * 2 + 1];
            }
            out[(size_t)rowg * 2 + 0] = o0;
            out[(size_t)rowg * 2 + 1] = o1;
        }
    }
}

extern "C" void kernel_launch(void* const* d_in, const int* in_sizes, int n_in,
                              void* d_out, int out_size, void* d_ws, size_t ws_size,
                              hipStream_t stream) {
    const float* x = (const float*)d_in[0];
    const int* ei = (const int*)d_in[1];
    const float* gamma = (const float*)d_in[6];
    const float* beta = (const float*)d_in[7];
    const float* Wl = (const float*)d_in[8];
    const float* bl = (const float*)d_in[9];
    const float* Wr = (const float*)d_in[10];
    const float* W1 = (const float*)d_in[11];
    const float* b1 = (const float*)d_in[12];
    const float* W2 = (const float*)d_in[13];
    const float* b2 = (const float*)d_in[14];

    int N = in_sizes[0] / FEAT;   // 100000
    int E = in_sizes[1] / 2;      // 1200000
    int nb = (N + 127) >> BSH;    // 782 coarse buckets

    float* ws = (float*)d_ws;
    int* wsi = (int*)d_ws;
    int bcOff = 256;                       // 1024 ints
    int bsOff = bcOff + NB_MAX;            // 1025 ints
    int pcOff = bsOff + NB_MAX + 32;       // 1024 ints
    int wcOff = (pcOff + NB_MAX + 3) & ~3; // 8192 floats (Wc: 16384 ushorts)
    int xnOff = wcOff + 8192;              // N*32 floats
    int aggOff = xnOff + N * 32;           // N*32 floats
    int pairsOff = aggOff + N * 32;        // E ints

    unsigned short* xnp = (unsigned short*)(ws + xnOff);
    unsigned short* aggp = (unsigned short*)(ws + aggOff);
    unsigned short* wcp = (unsigned short*)(ws + wcOff);
    int* pairs = wsi + pairsOff;

    float* out = (float*)d_out;
    int ebin = (E + CHUNK - 1) / CHUNK;

    hipLaunchKernelGGL(k0_zero, dim3(8), dim3(256), 0, stream, ws);
    hipLaunchKernelGGL(k1_stats, dim3(1024), dim3(256), 0, stream, x, ws, N);
    hipLaunchKernelGGL(k2_finalize, dim3(1), dim3(64), 0, stream, ws, gamma, beta, N);
    hipLaunchKernelGGL(kw_conv, dim3(64), dim3(256), 0, stream, Wl, Wr, wcp);
    hipLaunchKernelGGL(k3_norm, dim3(2048), dim3(256), 0, stream, x, ws, xnp, N);

    hipLaunchKernelGGL(kbh, dim3(ebin), dim3(256), 0, stream, ei, wsi + bcOff, E, nb);
    hipLaunchKernelGGL(kbscan, dim3(1), dim3(1024), 0, stream,
                       wsi + bcOff, wsi + bsOff, wsi + pcOff, nb);
    hipLaunchKernelGGL(kc_bin, dim3(ebin), dim3(256), 0, stream, ei, wsi + pcOff,
                       pairs, E, nb);
    hipLaunchKernelGGL(kda, dim3(nb), dim3(256), 0, stream, pairs, wsi + bsOff,
                       xnp, aggp, N);

    hipLaunchKernelGGL(k5_gemm, dim3((N + 63) / 64), dim3(256), 0, stream,
                       aggp, xnp, wcp, bl, W1, b1, W2, b2, out, N);
}

// Round 8
// 354.520 us; speedup vs baseline: 1.5980x; 1.0212x over previous
//
#include <hip/hip_runtime.h>

#define FEAT 64
#define HDIM 128
#define BN_EPS 1e-5f

#define BSH 7          // 128 nodes per coarse bucket
#define NB_MAX 1024    // max buckets (N <= 131072)
#define CHUNK 8192     // edges per binning block
#define SEG 4096       // LDS pair capacity in kda

typedef __attribute__((ext_vector_type(8))) short bf16x8;
typedef __attribute__((ext_vector_type(4))) float f32x4;

__device__ inline unsigned short f2bf(float f) {
    union { float f; unsigned int u; } v;
    v.f = f;
    unsigned int r = (v.u + 0x7FFFu + ((v.u >> 16) & 1u)) >> 16;  // RNE
    return (unsigned short)r;
}
__device__ inline float bf2f(unsigned short b) {
    union { unsigned int u; float f; } v;
    v.u = ((unsigned int)b) << 16;
    return v.f;
}

// ---------------- K0: zero stats + bucketCnt ----------------
__global__ void k0_zero(float* __restrict__ ws) {
    int gid = blockIdx.x * blockDim.x + threadIdx.x;
    if (gid < 256 + NB_MAX) ws[gid] = 0.0f;
}

// ---------------- K1: column sums / sumsq ----------------
__global__ __launch_bounds__(256) void k1_stats(const float* __restrict__ x,
                                                float* __restrict__ ws, int N) {
    int col = threadIdx.x & 63;
    int rowInBlk = threadIdx.x >> 6;
    float s = 0.f, sq = 0.f;
    for (int r = blockIdx.x * 4 + rowInBlk; r < N; r += gridDim.x * 4) {
        float v = x[(size_t)r * FEAT + col];
        s += v;
        sq += v * v;
    }
    __shared__ float sd[256];
    __shared__ float sd2[256];
    sd[threadIdx.x] = s;
    sd2[threadIdx.x] = sq;
    __syncthreads();
    if (threadIdx.x < 64) {
        s = sd[col] + sd[col + 64] + sd[col + 128] + sd[col + 192];
        sq = sd2[col] + sd2[col + 64] + sd2[col + 128] + sd2[col + 192];
        atomicAdd(&ws[col], s);
        atomicAdd(&ws[64 + col], sq);
    }
}

// ---------------- K2: finalize scale/shift ----------------
__global__ void k2_finalize(float* __restrict__ ws, const float* __restrict__ gamma,
                            const float* __restrict__ beta, int N) {
    int c = threadIdx.x;  // 64 threads
    float invN = 1.0f / (float)N;
    float mean = ws[c] * invN;
    float var = ws[64 + c] * invN - mean * mean;
    float sc = rsqrtf(var + BN_EPS) * gamma[c];
    ws[128 + c] = sc;
    ws[192 + c] = beta[c] - mean * sc;
}

// ---------------- K3: xn = bf16(x*scale + shift) ----------------
__global__ __launch_bounds__(256) void k3_norm(const float* __restrict__ x,
                                               const float* __restrict__ ws,
                                               unsigned short* __restrict__ xn, int N) {
    const float4* x4 = (const float4*)x;
    ushort4* o4 = (ushort4*)xn;
    int n4 = N * (FEAT / 4);
    int stride = gridDim.x * blockDim.x;
    for (int i = blockIdx.x * blockDim.x + threadIdx.x; i < n4; i += stride) {
        int cg = (i & 15) << 2;
        float4 v = x4[i];
        float4 sc = *(const float4*)(ws + 128 + cg);
        float4 sh = *(const float4*)(ws + 192 + cg);
        ushort4 o;
        o.x = f2bf(v.x * sc.x + sh.x);
        o.y = f2bf(v.y * sc.y + sh.y);
        o.z = f2bf(v.z * sc.z + sh.z);
        o.w = f2bf(v.w * sc.w + sh.w);
        o4[i] = o;
    }
}

// ---------------- KW: pack weights, MFMA-fragment order ----------------
__global__ __launch_bounds__(256) void kw_conv(const float* __restrict__ Wl,
                                               const float* __restrict__ Wr,
                                               unsigned short* __restrict__ Wc) {
    int id = blockIdx.x * 256 + threadIdx.x;  // 16384 total
    int n = id >> 7, k = id & 127;
    float w = (k < 64) ? Wl[k * HDIM + n] : Wr[(k - 64) * HDIM + n];
    Wc[((k >> 5) * 128 + n) * 32 + (k & 31)] = f2bf(w);
}

// ---------------- KBH: bucket histogram, block-aggregated ----------------
__global__ __launch_bounds__(256) void kbh(const int* __restrict__ ei,
                                           int* __restrict__ bktCnt, int E, int nb) {
    __shared__ int hist[NB_MAX];
    int e0 = blockIdx.x * CHUNK;
    int e1 = min(E, e0 + CHUNK);
    for (int b = threadIdx.x; b < nb; b += 256) hist[b] = 0;
    __syncthreads();
    for (int e = e0 + threadIdx.x; e < e1; e += 256)
        atomicAdd(&hist[((unsigned)ei[E + e]) >> BSH], 1);
    __syncthreads();
    for (int b = threadIdx.x; b < nb; b += 256) {
        int c = hist[b];
        if (c) atomicAdd(&bktCnt[b], c);
    }
}

// ---------------- KBSCAN: scan bucket counts, init cursors ----------------
__global__ __launch_bounds__(1024) void kbscan(const int* __restrict__ bktCnt,
                                               int* __restrict__ bktStart,
                                               int* __restrict__ pairCursor, int nb) {
    __shared__ int sd[1024];
    int t = threadIdx.x;
    int c = (t < nb) ? bktCnt[t] : 0;
    sd[t] = c;
    __syncthreads();
    int v = c;
    for (int off = 1; off < 1024; off <<= 1) {
        int add = (t >= off) ? sd[t - off] : 0;
        __syncthreads();
        v += add;
        sd[t] = v;
        __syncthreads();
    }
    if (t <= nb) {
        int st = v - c;  // exclusive prefix (t==nb -> total E)
        bktStart[t] = st;
        if (t < nb) pairCursor[t] = st;
    }
}

// ---------------- KC: coarse scatter, block-aggregated ----------------
__global__ __launch_bounds__(256) void kc_bin(const int* __restrict__ ei,
                                              int* __restrict__ pairCursor,
                                              int* __restrict__ pairs, int E, int nb) {
    __shared__ int hist[NB_MAX];
    __shared__ int base[NB_MAX];
    int e0 = blockIdx.x * CHUNK;
    int e1 = min(E, e0 + CHUNK);
    for (int b = threadIdx.x; b < nb; b += 256) hist[b] = 0;
    __syncthreads();
    for (int e = e0 + threadIdx.x; e < e1; e += 256)
        atomicAdd(&hist[((unsigned)ei[E + e]) >> BSH], 1);
    __syncthreads();
    for (int b = threadIdx.x; b < nb; b += 256) {
        int c = hist[b];
        base[b] = c ? atomicAdd(&pairCursor[b], c) : 0;
        hist[b] = 0;  // reuse as local cursor
    }
    __syncthreads();
    for (int e = e0 + threadIdx.x; e < e1; e += 256) {
        int src = ei[e];
        int dst = ei[E + e];
        int b = ((unsigned)dst) >> BSH;
        int off = atomicAdd(&hist[b], 1);
        pairs[base[b] + off] = (src << BSH) | (dst & 127);
    }
}

// ---------------- KDA: fused fine-group (LDS) + gather + mean ----------------
__global__ __launch_bounds__(256) void kda(const int* __restrict__ pairs,
                                           const int* __restrict__ bktStart,
                                           const unsigned short* __restrict__ xn,
                                           unsigned short* __restrict__ agg, int N) {
    __shared__ int sidx[SEG];
    __shared__ int cnt[128], nstart[128], ncur[128], buf[128];
    int b = blockIdx.x;
    int base = b << BSH;
    int bs = bktStart[b], be = bktStart[b + 1];
    int total = be - bs;
    int t = threadIdx.x;
    int lane = t & 63, wv = t >> 6;
    int part = lane & 7, slot = lane >> 3;

    if (total <= SEG) {
        if (t < 128) cnt[t] = 0;
        __syncthreads();
        for (int i = bs + t; i < be; i += 256)
            atomicAdd(&cnt[pairs[i] & 127], 1);
        __syncthreads();
        int v = 0, c = 0;
        if (t < 128) { c = cnt[t]; buf[t] = c; }
        __syncthreads();
        v = c;
        for (int off = 1; off < 128; off <<= 1) {
            int add = (t < 128 && t >= off) ? buf[t - off] : 0;
            __syncthreads();
            if (t < 128) { v += add; buf[t] = v; }
            __syncthreads();
        }
        if (t < 128) {
            nstart[t] = v - c;
            ncur[t] = v - c;
        }
        __syncthreads();
        for (int i = bs + t; i < be; i += 256) {
            int p = pairs[i];
            int nid = p & 127;
            int pos = atomicAdd(&ncur[nid], 1);
            sidx[pos] = (p >> BSH) << 6;  // src row offset in ushorts
        }
        __syncthreads();
        for (int ni = wv; ni < 128; ni += 4) {
            int node = base + ni;
            if (node >= N) continue;
            int st = nstart[ni];
            int deg = cnt[ni];
            float acc[8];
#pragma unroll
            for (int j = 0; j < 8; j++) acc[j] = 0.f;
            for (int e = 0; e < deg; e += 8) {
                if (e + slot < deg) {
                    int s = sidx[st + e + slot];
                    bf16x8 vx = *(const bf16x8*)(xn + s + part * 8);
#pragma unroll
                    for (int j = 0; j < 8; j++) acc[j] += bf2f((unsigned short)vx[j]);
                }
            }
#pragma unroll
            for (int m = 8; m <= 32; m <<= 1)
#pragma unroll
                for (int j = 0; j < 8; j++) acc[j] += __shfl_xor(acc[j], m);
            if (slot == 0) {
                float dinv = (deg > 0) ? (1.0f / (float)deg) : 0.0f;
                union { bf16x8 v; unsigned short u[8]; } o;
#pragma unroll
                for (int j = 0; j < 8; j++) o.u[j] = f2bf(acc[j] * dinv);
                *(bf16x8*)(agg + (size_t)node * FEAT + part * 8) = o.v;
            }
        }
    } else {
        for (int ni = wv; ni < 128; ni += 4) {
            int node = base + ni;
            if (node >= N) continue;
            float acc = 0.f;
            int deg = 0;
            for (int i = bs; i < be; i++) {
                int p = pairs[i];
                if ((p & 127) == ni) {
                    acc += bf2f(xn[((p >> BSH) << 6) + lane]);
                    deg++;
                }
            }
            float dinv = (deg > 0) ? (1.0f / (float)deg) : 0.0f;
            agg[(size_t)node * FEAT + lane] = f2bf(acc * dinv);
        }
    }
}

// ---------------- K5: MFMA GEMM (bf16) + fused head ----------------
// A-frag loads for ALL four kt hoisted ahead of compute: 8 HBM loads in
// flight per wave (latency-bound fix). B frags (L2-resident Wc) per-kt.
#define HS 133  // h_s row stride (floats)

__global__ __launch_bounds__(256, 4) void k5_gemm(
    const unsigned short* __restrict__ agg, const unsigned short* __restrict__ xn,
    const unsigned short* __restrict__ Wc, const float* __restrict__ bl,
    const float* __restrict__ W1, const float* __restrict__ b1,
    const float* __restrict__ W2, const float* __restrict__ b2,
    float* __restrict__ out, int N) {
    __shared__ float h_s[64 * HS];  // ~34 KB
    int t = threadIdx.x;
    int lane = t & 63;
    int wv = t >> 6;
    int rh = wv & 1;
    int ch = wv >> 1;
    int c = lane & 15;
    int q = lane >> 4;
    int row0 = blockIdx.x * 64;

    // ---- hoisted A-frag loads: af[kt][rt], all 8 issued before any use ----
    bf16x8 af[4][2];
    int rowi[2];
#pragma unroll
    for (int rt = 0; rt < 2; rt++) {
        int row = row0 + rh * 32 + rt * 16 + c;
        rowi[rt] = min(row, N - 1);  // clamp; tail rows discarded at store
    }
#pragma unroll
    for (int kt = 0; kt < 4; kt++) {
        const unsigned short* src = (kt < 2) ? agg : xn;
        int ko = (kt & 1) * 32 + q * 8;
#pragma unroll
        for (int rt = 0; rt < 2; rt++)
            af[kt][rt] = *(const bf16x8*)(src + (size_t)rowi[rt] * FEAT + ko);
    }

    f32x4 acc[2][4];
    f32x4 z = {0.f, 0.f, 0.f, 0.f};
#pragma unroll
    for (int rt = 0; rt < 2; rt++)
#pragma unroll
        for (int nt = 0; nt < 4; nt++) acc[rt][nt] = z;

#pragma unroll
    for (int kt = 0; kt < 4; kt++) {
        bf16x8 bfr[4];
#pragma unroll
        for (int nt = 0; nt < 4; nt++) {
            int col = ch * 64 + nt * 16 + c;
            bfr[nt] = *(const bf16x8*)(Wc + ((size_t)kt * 128 + col) * 32 + q * 8);
        }
#pragma unroll
        for (int rt = 0; rt < 2; rt++)
#pragma unroll
            for (int nt = 0; nt < 4; nt++)
                acc[rt][nt] = __builtin_amdgcn_mfma_f32_16x16x32_bf16(
                    af[kt][rt], bfr[nt], acc[rt][nt], 0, 0, 0);
    }

#pragma unroll
    for (int rt = 0; rt < 2; rt++) {
        int rbase = rh * 32 + rt * 16 + q * 4;
#pragma unroll
        for (int nt = 0; nt < 4; nt++) {
            int col = ch * 64 + nt * 16 + c;
            float bias = bl[col];
#pragma unroll
            for (int r = 0; r < 4; r++)
                h_s[(rbase + r) * HS + col] = fmaxf(acc[rt][nt][r] + bias, 0.f);
        }
    }
    __syncthreads();

    int row = t & 63;
    int jg = t >> 6;
    int j0 = jg * 32;
    float tp[16];
#pragma unroll
    for (int m = 0; m < 16; m++) tp[m] = 0.f;
    for (int jj = 0; jj < 32; jj++) {
        float hv = h_s[row * HS + j0 + jj];
        const float4* w14 = (const float4*)(W1 + (j0 + jj) * 16);
#pragma unroll
        for (int qq = 0; qq < 4; qq++) {
            float4 w1 = w14[qq];
            tp[4 * qq + 0] += hv * w1.x;
            tp[4 * qq + 1] += hv * w1.y;
            tp[4 * qq + 2] += hv * w1.z;
            tp[4 * qq + 3] += hv * w1.w;
        }
    }
    __syncthreads();
#pragma unroll
    for (int m = 0; m < 16; m++) h_s[row * HS + jg * 16 + m] = tp[m];
    __syncthreads();

    if (t < 64) {
        int rowg = row0 + t;
        if (rowg < N) {
            float o0 = b2[0], o1 = b2[1];
#pragma unroll
            for (int m = 0; m < 16; m++) {
                float tm = b1[m] + h_s[t * HS + m] + h_s[t * HS + 16 + m] +
                           h_s[t * HS + 32 + m] + h_s[t * HS + 48 + m];
                tm = fmaxf(tm, 0.f);
                o0 += tm * W2[m * 2 + 0];
                o1 += tm * W2[m * 2 + 1];
            }
            out[(size_t)rowg * 2 + 0] = o0;
            out[(size_t)rowg * 2 + 1] = o1;
        }
    }
}

extern "C" void kernel_launch(void* const* d_in, const int* in_sizes, int n_in,
                              void* d_out, int out_size, void* d_ws, size_t ws_size,
                              hipStream_t stream) {
    const float* x = (const float*)d_in[0];
    const int* ei = (const int*)d_in[1];
    const float* gamma = (const float*)d_in[6];
    const float* beta = (const float*)d_in[7];
    const float* Wl = (const float*)d_in[8];
    const float* bl = (const float*)d_in[9];
    const float* Wr = (const float*)d_in[10];
    const float* W1 = (const float*)d_in[11];
    const float* b1 = (const float*)d_in[12];
    const float* W2 = (const float*)d_in[13];
    const float* b2 = (const float*)d_in[14];

    int N = in_sizes[0] / FEAT;   // 100000
    int E = in_sizes[1] / 2;      // 1200000
    int nb = (N + 127) >> BSH;    // 782 coarse buckets

    float* ws = (float*)d_ws;
    int* wsi = (int*)d_ws;
    int bcOff = 256;                       // 1024 ints
    int bsOff = bcOff + NB_MAX;            // 1025 ints
    int pcOff = bsOff + NB_MAX + 32;       // 1024 ints
    int wcOff = (pcOff + NB_MAX + 3) & ~3; // 8192 floats (Wc: 16384 ushorts)
    int xnOff = wcOff + 8192;              // N*32 floats
    int aggOff = xnOff + N * 32;           // N*32 floats
    int pairsOff = aggOff + N * 32;        // E ints

    unsigned short* xnp = (unsigned short*)(ws + xnOff);
    unsigned short* aggp = (unsigned short*)(ws + aggOff);
    unsigned short* wcp = (unsigned short*)(ws + wcOff);
    int* pairs = wsi + pairsOff;

    float* out = (float*)d_out;
    int ebin = (E + CHUNK - 1) / CHUNK;

    hipLaunchKernelGGL(k0_zero, dim3(8), dim3(256), 0, stream, ws);
    hipLaunchKernelGGL(k1_stats, dim3(1024), dim3(256), 0, stream, x, ws, N);
    hipLaunchKernelGGL(k2_finalize, dim3(1), dim3(64), 0, stream, ws, gamma, beta, N);
    hipLaunchKernelGGL(kw_conv, dim3(64), dim3(256), 0, stream, Wl, Wr, wcp);
    hipLaunchKernelGGL(k3_norm, dim3(2048), dim3(256), 0, stream, x, ws, xnp, N);

    hipLaunchKernelGGL(kbh, dim3(ebin), dim3(256), 0, stream, ei, wsi + bcOff, E, nb);
    hipLaunchKernelGGL(kbscan, dim3(1), dim3(1024), 0, stream,
                       wsi + bcOff, wsi + bsOff, wsi + pcOff, nb);
    hipLaunchKernelGGL(kc_bin, dim3(ebin), dim3(256), 0, stream, ei, wsi + pcOff,
                       pairs, E, nb);
    hipLaunchKernelGGL(kda, dim3(nb), dim3(256), 0, stream, pairs, wsi + bsOff,
                       xnp, aggp, N);

    hipLaunchKernelGGL(k5_gemm, dim3((N + 63) / 64), dim3(256), 0, stream,
                       aggp, xnp, wcp, bl, W1, b1, W2, b2, out, N);
}